// Round 1
// baseline (2943.245 us; speedup 1.0000x reference)
//
#include <hip/hip_runtime.h>

// FNO spectral conv: B=32, L=4096, D=E=512, MODES=64.
// out = irfft( einsum("bmd,dem->bme", rfft(q)[:, :64, :], Wr + i*Wi), n=L )
//
// Decomposed into truncated-DFT GEMMs (only 64 of 2049 modes survive):
//   S1: F[b,d,m] (cplx) = sum_l q[b,l,d] * exp(-2pi i m l / L)
//   S2: G[b,m,e] (cplx) = sum_d F * (Wr + i Wi)[d,e,m]
//   S3: out[b,l,e] = (1/L)*Gr[b,0,e] + sum_{m>=1} (2/L)(Gr*cos - Gi*sin)(2pi m l/L)
// (irfft ignores Im of the DC bin; no Nyquist term since 64 << L/2.)

#define NB 32
#define NL 4096
#define ND 512
#define NE 512
#define NM 64

#define FELEMS (NB * ND * NM)   // float2 elements in one F buffer  (1,048,576)
#define HELEMS (NB * 128 * NE)  // float  elements in one H buffer  (2,097,152)

// ---------------------------------------------------------------- basis tables
// fwdT[l][k], k<64: cos(2pi k l/L); k>=64: -sin(2pi (k-64) l/L)   (rfft kernel)
// invT[l][k], k<64: cos(2pi k l/L); k>=64: +sin(2pi (k-64) l/L)   (synthesis)
__global__ __launch_bounds__(256) void build_tables_k(float* __restrict__ fwdT,
                                                      float* __restrict__ invT) {
  int idx = blockIdx.x * 256 + threadIdx.x;
  if (idx >= NL * NM) return;
  int l = idx >> 6, m = idx & (NM - 1);
  int p = (m * l) & (NL - 1);           // exact phase reduction mod L
  double s, c;
  sincospi((double)p / (double)(NL / 2), &s, &c);
  fwdT[l * 128 + m]      = (float)c;
  fwdT[l * 128 + 64 + m] = (float)(-s);
  invT[l * 128 + m]      = (float)c;
  invT[l * 128 + 64 + m] = (float)s;
}

// ---------------------------------------------------------------- stage 1
// One wave per (64-wide d tile, b, l-chunk). lane = d. Basis reads are
// wave-uniform -> scalar loads. Writes partial Fp[chunk][b][d][m] (float2).
__global__ __launch_bounds__(64) void stage1_k(const float* __restrict__ q,
                                               const float* __restrict__ fwdT,
                                               float2* __restrict__ Fp,
                                               int lchunk) {
  const int lane = threadIdx.x;
  const int d = blockIdx.x * 64 + lane;
  const int b = blockIdx.y;
  const int c = blockIdx.z;
  const int l0 = c * lchunk;
  float accr[NM], acci[NM];
#pragma unroll
  for (int m = 0; m < NM; ++m) { accr[m] = 0.f; acci[m] = 0.f; }
  const float* qp = q + ((size_t)b * NL) * ND + d;
  for (int l = l0; l < l0 + lchunk; ++l) {
    float qv = qp[(size_t)l * ND];
    const float* bs = fwdT + l * 128;
#pragma unroll
    for (int m = 0; m < NM; ++m) {
      accr[m] = fmaf(qv, bs[m],      accr[m]);   // +cos
      acci[m] = fmaf(qv, bs[64 + m], acci[m]);   // -sin  (table holds -sin)
    }
  }
  float2* o = Fp + (size_t)c * FELEMS + ((size_t)b * ND + d) * NM;
#pragma unroll
  for (int m = 0; m < NM; ++m) o[m] = make_float2(accr[m], acci[m]);
}

__global__ __launch_bounds__(256) void reduceF_k(const float2* __restrict__ Fp,
                                                 float2* __restrict__ Ft, int FS) {
  int idx = blockIdx.x * 256 + threadIdx.x;
  if (idx >= FELEMS) return;
  float xr = 0.f, xi = 0.f;
  for (int c = 0; c < FS; ++c) {
    float2 v = Fp[(size_t)c * FELEMS + idx];
    xr += v.x; xi += v.y;
  }
  Ft[idx] = make_float2(xr, xi);
}

// ---------------------------------------------------------------- stage 2
// lane = mode (the coalesced direction of W[D][E][64]). Each wave: 8 batches x
// 8 e-columns in registers; block = 4 waves covering all 32 batches of one
// 8-e tile, sharing W through L1. d-split over blockIdx.y into partials.
__global__ __launch_bounds__(256) void stage2_k(const float2* __restrict__ Ft,
                                                const float* __restrict__ Wr,
                                                const float* __restrict__ Wi,
                                                float* __restrict__ Hp,
                                                int dlen) {
  const int lane = threadIdx.x & 63;  // mode
  const int bg   = threadIdx.x >> 6;  // batch group (8 batches)
  const int e0 = blockIdx.x * 8;
  const int c  = blockIdx.y;
  const int d0 = c * dlen;
  float accr[8][8], acci[8][8];
#pragma unroll
  for (int jb = 0; jb < 8; ++jb)
#pragma unroll
    for (int je = 0; je < 8; ++je) { accr[jb][je] = 0.f; acci[jb][je] = 0.f; }

  for (int d = d0; d < d0 + dlen; ++d) {
    float wr[8], wi[8];
#pragma unroll
    for (int je = 0; je < 8; ++je) {
      size_t widx = ((size_t)d * NE + (e0 + je)) * NM + lane;
      wr[je] = Wr[widx];
      wi[je] = Wi[widx];
    }
#pragma unroll
    for (int jb = 0; jb < 8; ++jb) {
      float2 f = Ft[((size_t)(bg * 8 + jb) * ND + d) * NM + lane];
#pragma unroll
      for (int je = 0; je < 8; ++je) {
        accr[jb][je] = fmaf(f.x,  wr[je], accr[jb][je]);
        accr[jb][je] = fmaf(-f.y, wi[je], accr[jb][je]);
        acci[jb][je] = fmaf(f.x,  wi[je], acci[jb][je]);
        acci[jb][je] = fmaf(f.y,  wr[je], acci[jb][je]);
      }
    }
  }
  // Hp[c][b][k][e]: k<64 holds Gr (real), k>=64 holds Gi (imag), unscaled.
#pragma unroll
  for (int jb = 0; jb < 8; ++jb) {
    int b = bg * 8 + jb;
    size_t base = (size_t)c * HELEMS + ((size_t)b * 128) * NE;
#pragma unroll
    for (int je = 0; je < 8; ++je) {
      Hp[base + (size_t)lane * NE + (e0 + je)]        = accr[jb][je];
      Hp[base + (size_t)(64 + lane) * NE + (e0 + je)] = acci[jb][je];
    }
  }
}

// Reduce d-split partials and fold in the irfft scaling:
//   k<64  (cos coeff):  (k==0 ? 1 : 2)/L * Gr
//   k>=64 (sin coeff):  (m==0 ? 0 : -2/L) * Gi      (DC imag dropped by irfft)
__global__ __launch_bounds__(256) void reduceH_k(const float* __restrict__ Hp,
                                                 float* __restrict__ H, int DS) {
  int idx = blockIdx.x * 256 + threadIdx.x;
  if (idx >= HELEMS) return;
  float s = 0.f;
  for (int c = 0; c < DS; ++c) s += Hp[(size_t)c * HELEMS + idx];
  int k = (idx >> 9) & 127;
  float scale;
  if (k < 64) scale = (k == 0 ? 1.0f : 2.0f) / (float)NL;
  else        scale = (k == 64 ? 0.0f : -2.0f / (float)NL);
  H[idx] = s * scale;
}

// ---------------------------------------------------------------- stage 3
// One wave per (64-wide e tile, b, l-chunk). lane = e. H column (128 floats)
// lives in VGPRs; basis reads wave-uniform. 4 independent FMA chains.
__global__ __launch_bounds__(64) void stage3_k(const float* __restrict__ H,
                                               const float* __restrict__ invT,
                                               float* __restrict__ out) {
  const int lane = threadIdx.x;
  const int e = blockIdx.x * 64 + lane;
  const int b = blockIdx.y;
  const int l0 = blockIdx.z * (NL / 8);
  float h[128];
  const float* hp = H + ((size_t)b * 128) * NE + e;
#pragma unroll
  for (int k = 0; k < 128; ++k) h[k] = hp[(size_t)k * NE];
  float* op = out + ((size_t)b * NL) * NE + e;
  for (int l = l0; l < l0 + NL / 8; ++l) {
    const float* bs = invT + l * 128;
    float a0 = 0.f, a1 = 0.f, a2 = 0.f, a3 = 0.f;
#pragma unroll
    for (int k = 0; k < 32; ++k) {
      a0 = fmaf(bs[k],      h[k],      a0);
      a1 = fmaf(bs[32 + k], h[32 + k], a1);
      a2 = fmaf(bs[64 + k], h[64 + k], a2);
      a3 = fmaf(bs[96 + k], h[96 + k], a3);
    }
    op[(size_t)l * NE] = (a0 + a1) + (a2 + a3);
  }
}

// ---------------------------------------------------------------- launch
extern "C" void kernel_launch(void* const* d_in, const int* in_sizes, int n_in,
                              void* d_out, int out_size, void* d_ws, size_t ws_size,
                              hipStream_t stream) {
  const float* q  = (const float*)d_in[0];
  const float* Wr = (const float*)d_in[1];
  const float* Wi = (const float*)d_in[2];
  float* out = (float*)d_out;
  float* ws  = (float*)d_ws;

  // ws layout (floats): fwdT | invT | Ft | H | scratch(Fp or Hp)
  float*  fwdT = ws;                            // 524,288
  float*  invT = ws + 524288;                   // 524,288
  float2* Ft   = (float2*)(ws + 1048576);       // 1,048,576 float2
  float*  H    = ws + 1048576 + 2097152;        // 2,097,152
  float*  scratch = ws + 1048576 + 2097152 + 2097152;

  const size_t base_bytes = (size_t)(1048576 + 2097152 + 2097152) * 4u;
  const size_t CH = (size_t)HELEMS * 4u;        // 8,388,608 B per scratch chunk
  int FS = 1, DS = 1;                           // l-split / d-split factors
  if (ws_size >= base_bytes + 8 * CH)      { FS = 8; DS = 4; }
  else if (ws_size >= base_bytes + 4 * CH) { FS = 4; DS = 4; }
  else if (ws_size >= base_bytes + 2 * CH) { FS = 2; DS = 2; }

  build_tables_k<<<(NL * NM + 255) / 256, 256, 0, stream>>>(fwdT, invT);
  stage1_k<<<dim3(ND / 64, NB, FS), 64, 0, stream>>>(q, fwdT, (float2*)scratch,
                                                     NL / FS);
  reduceF_k<<<(FELEMS + 255) / 256, 256, 0, stream>>>((const float2*)scratch,
                                                      Ft, FS);
  stage2_k<<<dim3(NE / 8, DS), 256, 0, stream>>>(Ft, Wr, Wi, scratch, ND / DS);
  reduceH_k<<<(HELEMS + 255) / 256, 256, 0, stream>>>(scratch, H, DS);
  stage3_k<<<dim3(NE / 64, NB, 8), 64, 0, stream>>>(H, invT, out);
}